// Round 13
// baseline (483.121 us; speedup 1.0000x reference)
//
#include <hip/hip_runtime.h>
#include <hip/hip_fp16.h>

#define NCH 21
#define NCH2 22         // 21 Q-channels + channel 21 = weight-sum (norm)
#define VSH 32          // value row stride in halves (64B line)
#define QSH 32          // Q row stride in halves (64B line)
#define USH 24          // -U row stride in halves (48B, 16B-aligned rows)
#define NPIX (512*512)  // 2^18
#define DECODE12 (1.0f/(4095.f*128.f))
#define DECODE14 (1.0f/(16383.f*128.f))

__device__ __forceinline__ float2 bits2f2(float b) {
  __half2 h = __builtin_bit_cast(__half2, b);
  return __half22float2(h);
}
__device__ __forceinline__ float f22bits(float x, float y) {
  __half2 h = __floats2half2_rn(x, y);
  return __builtin_bit_cast(float, h);
}

// ---------------- wave-aggregated atomic rank ----------------
__device__ __forceinline__ int wave_rank_atomic(int m, bool valid, int* __restrict__ cur) {
  int lane = threadIdx.x & 63;
  unsigned long long todo = __ballot(valid);
  int out = 0;
  while (todo) {
    int leader = __ffsll((unsigned long long)todo) - 1;
    int lm = __shfl(m, leader);
    unsigned long long match = __ballot(valid && (m == lm));
    int cnt = __popcll(match);
    int b = 0;
    if (lane == leader) b = atomicAdd(&cur[lm], cnt);
    b = __shfl(b, leader);
    if (valid && (m == lm)) out = b + __popcll(match & ((1ull << lane) - 1ull));
    todo &= ~match;
  }
  return out;
}

// ---------------- build passes (slab order: t = j*NPIX + n) ----------------

__global__ void pack_count_kernel(const int* __restrict__ os_b, const float* __restrict__ ws_b,
                                  const int* __restrict__ os_s, const float* __restrict__ ws_s,
                                  unsigned int* __restrict__ sl, int* __restrict__ cnt,
                                  int nptot, int Mb) {
  int t = blockIdx.x*blockDim.x + threadIdx.x;
  bool valid = (t < nptot);
  int m = 0; float w = 0.f;
  if (valid) {
    if (t < 6*NPIX) { int j = t >> 18, n = t & (NPIX-1); m = os_b[n*6+j]; w = ws_b[n*6+j]; }
    else { int t2 = t - 6*NPIX; int j = t2 >> 18, n = t2 & (NPIX-1);
           m = Mb + os_s[n*3+j]; w = ws_s[n*3+j]; }
    int w12 = (int)(w * 4095.f + 0.5f);
    w12 = w12 < 0 ? 0 : (w12 > 4095 ? 4095 : w12);
    sl[t] = ((unsigned int)(m+1) << 12) | (unsigned int)w12;
  }
  int lane = threadIdx.x & 63;
  unsigned long long todo = __ballot(valid);
  while (todo) {
    int leader = __ffsll((unsigned long long)todo) - 1;
    int lm = __shfl(m, leader);
    unsigned long long match = __ballot(valid && (m == lm));
    if (lane == leader) atomicAdd(&cnt[lm], __popcll(match));
    todo &= ~match;
  }
}

__global__ void count_fused_kernel(const int* __restrict__ os_b, const int* __restrict__ os_s,
                                   int* __restrict__ cnt, int nptot, int Mb) {
  int t = blockIdx.x*blockDim.x + threadIdx.x;
  bool valid = (t < nptot);
  int m = 0;
  if (valid) {
    if (t < 6*NPIX) { int j = t >> 18, n = t & (NPIX-1); m = os_b[n*6+j]; }
    else { int t2 = t - 6*NPIX; int j = t2 >> 18, n = t2 & (NPIX-1); m = Mb + os_s[n*3+j]; }
  }
  int lane = threadIdx.x & 63;
  unsigned long long todo = __ballot(valid);
  while (todo) {
    int leader = __ffsll((unsigned long long)todo) - 1;
    int lm = __shfl(m, leader);
    unsigned long long match = __ballot(valid && (m == lm));
    if (lane == leader) atomicAdd(&cnt[lm], __popcll(match));
    todo &= ~match;
  }
}

__global__ void scan_block_kernel(const int* __restrict__ cnt, int* __restrict__ excl,
                                  int* __restrict__ bsum, int M) {
  __shared__ int s[256];
  int i = blockIdx.x*256 + threadIdx.x;
  int v = (i < M) ? cnt[i] : 0;
  s[threadIdx.x] = v;
  __syncthreads();
  for (int off = 1; off < 256; off <<= 1) {
    int t = (threadIdx.x >= off) ? s[threadIdx.x - off] : 0;
    __syncthreads();
    s[threadIdx.x] += t;
    __syncthreads();
  }
  if (i < M) excl[i] = s[threadIdx.x] - v;
  if (threadIdx.x == 255) bsum[blockIdx.x] = s[255];
}

__global__ void scan_sums_kernel(int* __restrict__ bsum, int nb) {
  __shared__ int s[256];
  __shared__ int carry;
  if (threadIdx.x == 0) carry = 0;
  __syncthreads();
  for (int base = 0; base < nb; base += 256) {
    int i = base + threadIdx.x;
    int v = (i < nb) ? bsum[i] : 0;
    s[threadIdx.x] = v;
    __syncthreads();
    for (int off = 1; off < 256; off <<= 1) {
      int t = (threadIdx.x >= off) ? s[threadIdx.x - off] : 0;
      __syncthreads();
      s[threadIdx.x] += t;
      __syncthreads();
    }
    if (i < nb) bsum[i] = s[threadIdx.x] - v + carry;
    int tot = s[255];
    __syncthreads();
    if (threadIdx.x == 0) carry += tot;
    __syncthreads();
  }
  if (threadIdx.x == 0) bsum[nb] = carry;
}

__global__ void scan_add_kernel(int* __restrict__ excl, const int* __restrict__ bsum,
                                int M, int nb) {
  int i = blockIdx.x*blockDim.x + threadIdx.x;
  if (i < M) excl[i] += bsum[i >> 8];
  else if (i == M) excl[M] = bsum[nb];
}

__global__ void fill_packed_kernel(const unsigned int* __restrict__ sl,
                                   const int* __restrict__ start, int* __restrict__ cur,
                                   unsigned int* __restrict__ pw, int nptot) {
  int t = blockIdx.x*blockDim.x + threadIdx.x;
  bool valid = (t < nptot);
  int m = 0; unsigned int e = 0;
  if (valid) {
    e = sl[t];
    m = (int)(e >> 12) - 1;
  }
  int slot = wave_rank_atomic(m, valid, cur);
  if (valid) {
    unsigned int pix = (unsigned int)(t & (NPIX-1));
    pw[start[m] + slot] = (pix << 12) | (e & 4095u);
  }
}

__global__ void fill_fused_kernel(const int* __restrict__ os_b, const float* __restrict__ ws_b,
                                  const int* __restrict__ os_s, const float* __restrict__ ws_s,
                                  const int* __restrict__ start, int* __restrict__ cur,
                                  unsigned int* __restrict__ pw, int nptot, int Mb) {
  int t = blockIdx.x*blockDim.x + threadIdx.x;
  bool valid = (t < nptot);
  int m = 0, pix = 0; float w = 0.f;
  if (valid) {
    if (t < 6*NPIX) { int j = t >> 18, n = t & (NPIX-1); m = os_b[n*6+j]; pix = n; w = ws_b[n*6+j]; }
    else { int t2 = t - 6*NPIX; int j = t2 >> 18, n = t2 & (NPIX-1);
           m = Mb + os_s[n*3+j]; pix = n; w = ws_s[n*3+j]; }
  }
  int slot = wave_rank_atomic(m, valid, cur);
  if (valid) {
    int w14 = (int)(w * 16383.f + 0.5f);
    w14 = w14 < 0 ? 0 : (w14 > 16383 ? 16383 : w14);
    pw[start[m] + slot] = ((unsigned int)pix << 14) | (unsigned int)w14;
  }
}

// ---------------- lattice ops ----------------

// packed gather splat, wave-per-lattice-point: 5 pair-groups x 11 half2 chunks
__global__ void gather_half2_kernel(const __half* __restrict__ Qh, const int* __restrict__ start,
                                    const unsigned int* __restrict__ pw,
                                    __half* __restrict__ valsB, __half* __restrict__ valsS,
                                    int Mb, int Mtot) {
  int wid = blockIdx.x*(blockDim.x >> 6) + (threadIdx.x >> 6);
  if (wid >= Mtot) return;
  int lane = threadIdx.x & 63;
  int pg = lane/11;                    // 0..5 (pg==5 -> lanes 55..63 idle)
  int c2 = lane - pg*11;               // half2 chunk 0..10
  int k0 = start[wid], k1 = start[wid+1];
  float ax = 0.f, ay = 0.f, wsum = 0.f;
  if (pg < 5) {
    int k = k0 + pg;
    for (; k + 5 < k1; k += 10) {
      unsigned int e0 = pw[k], e1 = pw[k+5];
      float w0 = (float)(e0 & 4095u), w1 = (float)(e1 & 4095u);
      float2 f0 = __half22float2(*(const __half2*)(Qh + ((size_t)(e0 >> 12) << 5) + 2*c2));
      float2 f1 = __half22float2(*(const __half2*)(Qh + ((size_t)(e1 >> 12) << 5) + 2*c2));
      ax += w0*f0.x + w1*f1.x;
      ay += w0*f0.y + w1*f1.y;
      wsum += w0 + w1;
    }
    if (k < k1) {
      unsigned int e0 = pw[k];
      float w0 = (float)(e0 & 4095u);
      float2 f0 = __half22float2(*(const __half2*)(Qh + ((size_t)(e0 >> 12) << 5) + 2*c2));
      ax += w0*f0.x; ay += w0*f0.y; wsum += w0;
    }
  }
  float sx = ax, sy = ay, wt = wsum;
  #pragma unroll
  for (int g = 1; g < 5; ++g) {
    sx += __shfl(ax, lane + 11*g);
    sy += __shfl(ay, lane + 11*g);
    wt += __shfl(wsum, lane + 11*g);
  }
  if (lane < 11) {
    __half* row = (wid < Mb) ? (valsB + (size_t)(wid+1)*VSH)
                             : (valsS + (size_t)(wid-Mb+1)*VSH);
    float hy = (lane == 10) ? wt : sy;   // value ch21 = weight sum (norm)
    *(__half2*)(row + 2*lane) = __floats2half2_rn(sx*DECODE12, hy*DECODE12);
  }
}

// fallback gather (14-bit pw), 3x21 scalar layout
__global__ void gather_wave_kernel(const __half* __restrict__ Qh, const int* __restrict__ start,
                                   const unsigned int* __restrict__ pw,
                                   __half* __restrict__ valsB, __half* __restrict__ valsS,
                                   int Mb, int Mtot) {
  const unsigned int WMASK = (1u << 14) - 1u;
  int wid = blockIdx.x*(blockDim.x >> 6) + (threadIdx.x >> 6);
  if (wid >= Mtot) return;
  int lane = threadIdx.x & 63;
  int pg = lane / 21;
  int c  = lane - pg*21;
  float s = 0.f, wsum = 0.f;
  int k1 = start[wid+1];
  if (pg < 3) {
    int k = start[wid] + pg;
    for (; k + 9 < k1; k += 12) {
      unsigned int a0 = pw[k], a1 = pw[k+3], a2 = pw[k+6], a3 = pw[k+9];
      float w0 = (float)(a0 & WMASK), w1 = (float)(a1 & WMASK);
      float w2 = (float)(a2 & WMASK), w3 = (float)(a3 & WMASK);
      s += w0 * __half2float(Qh[((size_t)(a0 >> 14) << 5) + c])
         + w1 * __half2float(Qh[((size_t)(a1 >> 14) << 5) + c])
         + w2 * __half2float(Qh[((size_t)(a2 >> 14) << 5) + c])
         + w3 * __half2float(Qh[((size_t)(a3 >> 14) << 5) + c]);
      wsum += w0 + w1 + w2 + w3;
    }
    for (; k < k1; k += 3) {
      unsigned int a = pw[k];
      float w = (float)(a & WMASK);
      s += w * __half2float(Qh[((size_t)(a >> 14) << 5) + c]);
      wsum += w;
    }
  }
  float s1 = __shfl(s, (lane + 21) & 63);
  float s2 = __shfl(s, (lane + 42) & 63);
  float wt = __shfl(wsum, 0) + __shfl(wsum, 21) + __shfl(wsum, 42);
  __half* row = (wid < Mb) ? (valsB + (size_t)(wid+1)*VSH)
                           : (valsS + (size_t)(wid-Mb+1)*VSH);
  if (lane < 21)       row[c]  = __float2half((s + s1 + s2) * DECODE14);
  else if (lane == 21) row[21] = __float2half(wt * DECODE14);
}

// blur: 4 threads per row, float4 (16B) chunks, fp32 math on half2 components.
// Pad halves (bytes 44..63) carry garbage through - never read as channels.
__global__ void blurH4_fused_kernel(const __half* __restrict__ inB, __half* __restrict__ outB,
                                    const int* __restrict__ bnB, int Mb,
                                    const __half* __restrict__ inS, __half* __restrict__ outS,
                                    const int* __restrict__ bnS, int Ms) {
  int t = blockIdx.x*blockDim.x + threadIdx.x;
  const __half* in; __half* out; const int* bn; int i, q;
  int tb = Mb*4;
  if (t < tb) { i = t>>2; q = t&3; in = inB; out = outB; bn = bnB; }
  else {
    int t2 = t - tb;
    if (t2 >= Ms*4) return;
    i = t2>>2; q = t2&3; in = inS; out = outS; bn = bnS;
  }
  int b0 = bn[2*i], b1 = bn[2*i+1];
  float4 A = ((const float4*)(in + (size_t)(i+1)*VSH))[q];
  float4 X = ((const float4*)(in + (size_t)b0*VSH))[q];
  float4 Y = ((const float4*)(in + (size_t)b1*VSH))[q];
  float4 O;
  const float* Af = (const float*)&A;
  const float* Xf = (const float*)&X;
  const float* Yf = (const float*)&Y;
  float* Of = (float*)&O;
  #pragma unroll
  for (int u = 0; u < 4; ++u) {
    float2 a = bits2f2(Af[u]);
    float2 x = bits2f2(Xf[u]);
    float2 y = bits2f2(Yf[u]);
    Of[u] = f22bits(a.x + 0.5f*(x.x + y.x), a.y + 0.5f*(x.y + y.y));
  }
  ((float4*)(out + (size_t)(i+1)*VSH))[q] = O;
}

// ---------------- pixel-side kernels ----------------

__global__ void softmax_init_kernel(const float* __restrict__ U, __half* __restrict__ Qh,
                                    __half* __restrict__ Uh) {
  int n = blockIdx.x*blockDim.x + threadIdx.x;
  if (n >= NPIX) return;
  float l[NCH];
  float m = -3.4e38f;
  #pragma unroll
  for (int c = 0; c < NCH; ++c) {
    l[c] = -U[(size_t)n*NCH+c];
    m = fmaxf(m, l[c]);
  }
  // vectorized Uh store: 10 half2 pairs + 1 (l20, 0)
  {
    float buf[11];
    #pragma unroll
    for (int i = 0; i < 10; ++i) buf[i] = f22bits(l[2*i], l[2*i+1]);
    buf[10] = f22bits(l[20], 0.f);
    __half* u = Uh + (size_t)n*USH;
    *(float4*)(u)      = *(float4*)&buf[0];
    *(float4*)(u + 8)  = *(float4*)&buf[4];
    *(float2*)(u + 16) = *(float2*)&buf[8];
    *(float*)(u + 20)  = buf[10];
  }
  float s = 0.f;
  #pragma unroll
  for (int c = 0; c < NCH; ++c) { l[c] = expf(l[c]-m); s += l[c]; }
  float r = 1.0f/s;
  #pragma unroll
  for (int c = 0; c < NCH; ++c) l[c] *= r;
  {
    float buf[11];
    #pragma unroll
    for (int i = 0; i < 10; ++i) buf[i] = f22bits(l[2*i], l[2*i+1]);
    buf[10] = f22bits(l[20], 0.f);   // ch21 = 0 for half2 gather
    __half* q = Qh + (size_t)n*QSH;
    *(float4*)(q)      = *(float4*)&buf[0];
    *(float4*)(q + 8)  = *(float4*)&buf[4];
    *(float2*)(q + 16) = *(float2*)&buf[8];
    *(float*)(q + 20)  = buf[10];
  }
}

// accumulate one 22-channel value row (4 wide loads) into acc2[11] (fp32)
__device__ __forceinline__ void accum_row(const __half* __restrict__ v, float w, float2* acc2) {
  float4 a = *(const float4*)(v);
  float4 b = *(const float4*)(v + 8);
  float2 c = *(const float2*)(v + 16);
  float  d = *(const float*)(v + 20);
  float buf[11] = {a.x, a.y, a.z, a.w, b.x, b.y, b.z, b.w, c.x, c.y, d};
  #pragma unroll
  for (int i = 0; i < 11; ++i) {
    float2 f = bits2f2(buf[i]);
    acc2[i].x += w*f.x;
    acc2[i].y += w*f.y;
  }
}

template<bool FINAL, bool PACKED>
__global__ void slice_combine_softmax_kernel(
    const __half* __restrict__ Uh,
    const __half* __restrict__ vb, const __half* __restrict__ vsShift,
    const unsigned int* __restrict__ sl,
    const float* __restrict__ ws_b, const int* __restrict__ os_b,
    const float* __restrict__ ws_s, const int* __restrict__ os_s,
    float* __restrict__ QoutF, __half* __restrict__ QoutH) {
  int n = blockIdx.x*blockDim.x + threadIdx.x;
  if (n >= NPIX) return;
  // vectorized Uh read (l = -U)
  float l[NCH];
  {
    const __half* u = Uh + (size_t)n*USH;
    float4 a = *(const float4*)(u);
    float4 b = *(const float4*)(u + 8);
    float2 c = *(const float2*)(u + 16);
    float buf[10] = {a.x, a.y, a.z, a.w, b.x, b.y, b.z, b.w, c.x, c.y};
    #pragma unroll
    for (int i = 0; i < 10; ++i) {
      float2 f = bits2f2(buf[i]);
      l[2*i] = f.x; l[2*i+1] = f.y;
    }
    l[20] = __half2float(u[20]);
  }
  float2 acc2[11];
  #pragma unroll
  for (int i = 0; i < 11; ++i) acc2[i] = make_float2(0.f, 0.f);
  #pragma unroll
  for (int j = 0; j < 6; ++j) {
    float w; const __half* v;
    if (PACKED) {
      unsigned int e = sl[(size_t)j*NPIX + n];
      w = (float)(e & 4095u);
      v = vb + ((size_t)(e >> 12) << 5);
    } else {
      w = ws_b[n*6+j];
      v = vb + (size_t)(os_b[n*6+j]+1)*VSH;
    }
    accum_row(v, w, acc2);
  }
  {
    float rb = 10.0f/(acc2[10].y + 1e-12f);   // ch21 = norm
    #pragma unroll
    for (int i = 0; i < 10; ++i) { l[2*i] += rb*acc2[i].x; l[2*i+1] += rb*acc2[i].y; }
    l[20] += rb*acc2[10].x;
  }
  #pragma unroll
  for (int i = 0; i < 11; ++i) acc2[i] = make_float2(0.f, 0.f);
  #pragma unroll
  for (int j = 0; j < 3; ++j) {
    float w; const __half* v;
    if (PACKED) {
      unsigned int e = sl[(size_t)(6+j)*NPIX + n];
      w = (float)(e & 4095u);
      v = vsShift + ((size_t)(e >> 12) << 5);
    } else {
      w = ws_s[n*3+j];
      v = vsShift + (size_t)(os_s[n*3+j]+1)*VSH;
    }
    accum_row(v, w, acc2);
  }
  {
    float rs = 3.0f/(acc2[10].y + 1e-12f);
    #pragma unroll
    for (int i = 0; i < 10; ++i) { l[2*i] += rs*acc2[i].x; l[2*i+1] += rs*acc2[i].y; }
    l[20] += rs*acc2[10].x;
  }
  float m = -3.4e38f;
  #pragma unroll
  for (int c = 0; c < NCH; ++c) m = fmaxf(m, l[c]);
  float s = 0.f;
  #pragma unroll
  for (int c = 0; c < NCH; ++c) { l[c] = expf(l[c]-m); s += l[c]; }
  float r = 1.0f/s;
  if (FINAL) {
    #pragma unroll
    for (int c = 0; c < NCH; ++c) QoutF[(size_t)n*NCH+c] = l[c]*r;
  } else {
    float buf[11];
    #pragma unroll
    for (int i = 0; i < 10; ++i) buf[i] = f22bits(l[2*i]*r, l[2*i+1]*r);
    buf[10] = f22bits(l[20]*r, 0.f);
    __half* q = QoutH + (size_t)n*QSH;
    *(float4*)(q)      = *(float4*)&buf[0];
    *(float4*)(q + 8)  = *(float4*)&buf[4];
    *(float2*)(q + 16) = *(float2*)&buf[8];
    *(float*)(q + 20)  = buf[10];
  }
}

// ---------------- host ----------------

extern "C" void kernel_launch(void* const* d_in, const int* in_sizes, int n_in,
                              void* d_out, int out_size, void* d_ws, size_t ws_size,
                              hipStream_t stream) {
  const float* U    = (const float*)d_in[0];
  const float* ws_b = (const float*)d_in[1];
  const float* ws_s = (const float*)d_in[2];
  const int*   os_b = (const int*)d_in[3];
  const int*   os_s = (const int*)d_in[4];
  const int*   bn_b = (const int*)d_in[5];
  const int*   bn_s = (const int*)d_in[6];
  const int Mb = in_sizes[5] / 12;
  const int Ms = in_sizes[6] / 6;
  const int Mtot = Mb + Ms;
  const int nptot = NPIX*9;
  const bool packed = (Mtot + 1) < (1 << 20);

  char* wcur = (char*)d_ws;
  auto alloc = [&](size_t bytes) -> void* {
    void* p = (void*)wcur;
    wcur += (bytes + 63) & ~(size_t)63;
    return p;
  };
  __half* Qh     = (__half*)alloc((size_t)NPIX*QSH*2);
  __half* Uh     = (__half*)alloc((size_t)NPIX*USH*2);
  __half* vAb    = (__half*)alloc((size_t)(Mb+1)*VSH*2);
  __half* vBb    = (__half*)alloc((size_t)(Mb+1)*VSH*2);
  __half* vAs    = (__half*)alloc((size_t)(Ms+1)*VSH*2);
  __half* vBs    = (__half*)alloc((size_t)(Ms+1)*VSH*2);
  int*   start   = (int*)alloc((size_t)(Mtot+1)*4);
  int*   cur     = (int*)alloc((size_t)Mtot*4);
  unsigned int* pw = (unsigned int*)alloc((size_t)nptot*4);
  unsigned int* sl = (unsigned int*)alloc((size_t)nptot*4);
  int*   bsum    = (int*)alloc((size_t)(Mtot/256 + 3)*4);

  const int TB = 256;
  auto blocks = [](long long n){ return (int)((n + 255)/256); };
  const int nbM = blocks(Mtot);

  // ---- build: pack+count (one pass), scan, fill ----
  hipMemsetAsync(cur, 0, (size_t)Mtot*sizeof(int), stream);
  if (packed)
    pack_count_kernel<<<blocks(nptot), TB, 0, stream>>>(os_b, ws_b, os_s, ws_s,
                                                        sl, cur, nptot, Mb);
  else
    count_fused_kernel<<<blocks(nptot), TB, 0, stream>>>(os_b, os_s, cur, nptot, Mb);
  scan_block_kernel<<<nbM, 256, 0, stream>>>(cur, start, bsum, Mtot);
  scan_sums_kernel<<<1, 256, 0, stream>>>(bsum, nbM);
  scan_add_kernel<<<blocks(Mtot+1), TB, 0, stream>>>(start, bsum, Mtot, nbM);
  hipMemsetAsync(cur, 0, (size_t)Mtot*sizeof(int), stream);
  if (packed)
    fill_packed_kernel<<<blocks(nptot), TB, 0, stream>>>(sl, start, cur, pw, nptot);
  else
    fill_fused_kernel<<<blocks(nptot), TB, 0, stream>>>(os_b, ws_b, os_s, ws_s,
                                                        start, cur, pw, nptot, Mb);

  // ---- zero sentinel row 0 of value buffers ----
  hipMemsetAsync(vAb, 0, VSH*2, stream);
  hipMemsetAsync(vBb, 0, VSH*2, stream);
  hipMemsetAsync(vAs, 0, VSH*2, stream);
  hipMemsetAsync(vBs, 0, VSH*2, stream);

  softmax_init_kernel<<<blocks(NPIX), TB, 0, stream>>>(U, Qh, Uh);

  for (int it = 0; it < 5; ++it) {
    if (packed)
      gather_half2_kernel<<<blocks((long long)Mtot*64), TB, 0, stream>>>(
          Qh, start, pw, vAb, vAs, Mb, Mtot);
    else
      gather_wave_kernel<<<blocks((long long)Mtot*64), TB, 0, stream>>>(
          Qh, start, pw, vAb, vAs, Mb, Mtot);
    __half* ab = vAb; __half* bb = vBb;
    __half* as = vAs; __half* bs = vBs;
    for (int j = 0; j < 6; ++j) {
      int ms = (j < 3) ? Ms : 0;
      blurH4_fused_kernel<<<blocks((long long)(Mb + ms)*4), TB, 0, stream>>>(
          ab, bb, bn_b + (size_t)j*Mb*2, Mb, as, bs, bn_s + (size_t)j*Ms*2, ms);
      { __half* t = ab; ab = bb; bb = t; }
      if (j < 3) { __half* t = as; as = bs; bs = t; }
    }
    // ab = final bilateral (vAb), as = final spatial (vBs)
    const __half* vsArg = packed ? (as - (size_t)Mb*VSH) : as;
    if (it == 4) {
      if (packed)
        slice_combine_softmax_kernel<true,true><<<blocks(NPIX), TB, 0, stream>>>(
            Uh, ab, vsArg, sl, ws_b, os_b, ws_s, os_s, (float*)d_out, (__half*)nullptr);
      else
        slice_combine_softmax_kernel<true,false><<<blocks(NPIX), TB, 0, stream>>>(
            Uh, ab, vsArg, sl, ws_b, os_b, ws_s, os_s, (float*)d_out, (__half*)nullptr);
    } else {
      if (packed)
        slice_combine_softmax_kernel<false,true><<<blocks(NPIX), TB, 0, stream>>>(
            Uh, ab, vsArg, sl, ws_b, os_b, ws_s, os_s, (float*)nullptr, Qh);
      else
        slice_combine_softmax_kernel<false,false><<<blocks(NPIX), TB, 0, stream>>>(
            Uh, ab, vsArg, sl, ws_b, os_b, ws_s, os_s, (float*)nullptr, Qh);
    }
  }
}

// Round 14
// 452.586 us; speedup vs baseline: 1.0675x; 1.0675x over previous
//
#include <hip/hip_runtime.h>
#include <hip/hip_fp16.h>

#define NCH 21
#define NCH2 22         // 21 Q-channels + channel 21 = weight-sum (norm)
#define VSH 32          // value row stride in halves (64B line)
#define QSH 32          // Q row stride in halves (64B line)
#define USH 24          // -U row stride in halves (48B, 16B-aligned rows)
#define NPIX (512*512)  // 2^18
#define DECODE12 (1.0f/(4095.f*128.f))
#define DECODE14 (1.0f/(16383.f*128.f))

__device__ __forceinline__ float2 bits2f2(float b) {
  __half2 h = __builtin_bit_cast(__half2, b);
  return __half22float2(h);
}
__device__ __forceinline__ float f22bits(float x, float y) {
  __half2 h = __floats2half2_rn(x, y);
  return __builtin_bit_cast(float, h);
}

// ---------------- wave-aggregated atomic rank ----------------
__device__ __forceinline__ int wave_rank_atomic(int m, bool valid, int* __restrict__ cur) {
  int lane = threadIdx.x & 63;
  unsigned long long todo = __ballot(valid);
  int out = 0;
  while (todo) {
    int leader = __ffsll((unsigned long long)todo) - 1;
    int lm = __shfl(m, leader);
    unsigned long long match = __ballot(valid && (m == lm));
    int cnt = __popcll(match);
    int b = 0;
    if (lane == leader) b = atomicAdd(&cur[lm], cnt);
    b = __shfl(b, leader);
    if (valid && (m == lm)) out = b + __popcll(match & ((1ull << lane) - 1ull));
    todo &= ~match;
  }
  return out;
}

// wave-aggregated count (all lanes valid)
__device__ __forceinline__ void wave_count_atomic(int m, int* __restrict__ cnt) {
  int lane = threadIdx.x & 63;
  unsigned long long todo = ~0ull;
  while (todo) {
    int leader = __ffsll((unsigned long long)todo) - 1;
    int lm = __shfl(m, leader);
    unsigned long long match = __ballot(m == lm);
    if (lane == leader) atomicAdd(&cnt[lm], __popcll(match & todo));
    todo &= ~match;
  }
}

// ---------------- build passes ----------------

// per-pixel pack+count: thread n reads its 6 bilateral + 3 spatial entries
// (contiguous int2/float2 loads), writes sl[j*NPIX+n] (9 coalesced streams),
// and does wave-aggregated count atomics per slab.
__global__ void pack9_count_kernel(const int* __restrict__ os_b, const float* __restrict__ ws_b,
                                   const int* __restrict__ os_s, const float* __restrict__ ws_s,
                                   unsigned int* __restrict__ sl, int* __restrict__ cnt,
                                   int Mb) {
  int n = blockIdx.x*blockDim.x + threadIdx.x;
  if (n >= NPIX) return;   // grid covers exactly NPIX (multiple of 64) - no divergence
  int ob[6]; float wb[6];
  {
    const int2* p = (const int2*)(os_b + (size_t)n*6);
    int2 a = p[0], b = p[1], c = p[2];
    ob[0]=a.x; ob[1]=a.y; ob[2]=b.x; ob[3]=b.y; ob[4]=c.x; ob[5]=c.y;
    const float2* q = (const float2*)(ws_b + (size_t)n*6);
    float2 d = q[0], e = q[1], f = q[2];
    wb[0]=d.x; wb[1]=d.y; wb[2]=e.x; wb[3]=e.y; wb[4]=f.x; wb[5]=f.y;
  }
  int osv[3]; float wsv[3];
  #pragma unroll
  for (int j = 0; j < 3; ++j) { osv[j] = os_s[(size_t)n*3+j]; wsv[j] = ws_s[(size_t)n*3+j]; }

  #pragma unroll
  for (int j = 0; j < 6; ++j) {
    int m = ob[j];
    int w12 = (int)(wb[j] * 4095.f + 0.5f);
    w12 = w12 < 0 ? 0 : (w12 > 4095 ? 4095 : w12);
    sl[(size_t)j*NPIX + n] = ((unsigned int)(m+1) << 12) | (unsigned int)w12;
    wave_count_atomic(m, cnt);
  }
  #pragma unroll
  for (int j = 0; j < 3; ++j) {
    int m = Mb + osv[j];
    int w12 = (int)(wsv[j] * 4095.f + 0.5f);
    w12 = w12 < 0 ? 0 : (w12 > 4095 ? 4095 : w12);
    sl[(size_t)(6+j)*NPIX + n] = ((unsigned int)(m+1) << 12) | (unsigned int)w12;
    wave_count_atomic(m, cnt);
  }
}

// fallback count (slab order)
__global__ void count_fused_kernel(const int* __restrict__ os_b, const int* __restrict__ os_s,
                                   int* __restrict__ cnt, int nptot, int Mb) {
  int t = blockIdx.x*blockDim.x + threadIdx.x;
  bool valid = (t < nptot);
  int m = 0;
  if (valid) {
    if (t < 6*NPIX) { int j = t >> 18, n = t & (NPIX-1); m = os_b[n*6+j]; }
    else { int t2 = t - 6*NPIX; int j = t2 >> 18, n = t2 & (NPIX-1); m = Mb + os_s[n*3+j]; }
  }
  int lane = threadIdx.x & 63;
  unsigned long long todo = __ballot(valid);
  while (todo) {
    int leader = __ffsll((unsigned long long)todo) - 1;
    int lm = __shfl(m, leader);
    unsigned long long match = __ballot(valid && (m == lm));
    if (lane == leader) atomicAdd(&cnt[lm], __popcll(match));
    todo &= ~match;
  }
}

__global__ void scan_block_kernel(const int* __restrict__ cnt, int* __restrict__ excl,
                                  int* __restrict__ bsum, int M) {
  __shared__ int s[256];
  int i = blockIdx.x*256 + threadIdx.x;
  int v = (i < M) ? cnt[i] : 0;
  s[threadIdx.x] = v;
  __syncthreads();
  for (int off = 1; off < 256; off <<= 1) {
    int t = (threadIdx.x >= off) ? s[threadIdx.x - off] : 0;
    __syncthreads();
    s[threadIdx.x] += t;
    __syncthreads();
  }
  if (i < M) excl[i] = s[threadIdx.x] - v;
  if (threadIdx.x == 255) bsum[blockIdx.x] = s[255];
}

__global__ void scan_sums_kernel(int* __restrict__ bsum, int nb) {
  __shared__ int s[256];
  __shared__ int carry;
  if (threadIdx.x == 0) carry = 0;
  __syncthreads();
  for (int base = 0; base < nb; base += 256) {
    int i = base + threadIdx.x;
    int v = (i < nb) ? bsum[i] : 0;
    s[threadIdx.x] = v;
    __syncthreads();
    for (int off = 1; off < 256; off <<= 1) {
      int t = (threadIdx.x >= off) ? s[threadIdx.x - off] : 0;
      __syncthreads();
      s[threadIdx.x] += t;
      __syncthreads();
    }
    if (i < nb) bsum[i] = s[threadIdx.x] - v + carry;
    int tot = s[255];
    __syncthreads();
    if (threadIdx.x == 0) carry += tot;
    __syncthreads();
  }
  if (threadIdx.x == 0) bsum[nb] = carry;
}

__global__ void scan_add_kernel(int* __restrict__ excl, const int* __restrict__ bsum,
                                int M, int nb) {
  int i = blockIdx.x*blockDim.x + threadIdx.x;
  if (i < M) excl[i] += bsum[i >> 8];
  else if (i == M) excl[M] = bsum[nb];
}

__global__ void fill_packed_kernel(const unsigned int* __restrict__ sl,
                                   const int* __restrict__ start, int* __restrict__ cur,
                                   unsigned int* __restrict__ pw, int nptot) {
  int t = blockIdx.x*blockDim.x + threadIdx.x;
  bool valid = (t < nptot);
  int m = 0; unsigned int e = 0;
  if (valid) {
    e = sl[t];
    m = (int)(e >> 12) - 1;
  }
  int slot = wave_rank_atomic(m, valid, cur);
  if (valid) {
    unsigned int pix = (unsigned int)(t & (NPIX-1));
    pw[start[m] + slot] = (pix << 12) | (e & 4095u);
  }
}

__global__ void fill_fused_kernel(const int* __restrict__ os_b, const float* __restrict__ ws_b,
                                  const int* __restrict__ os_s, const float* __restrict__ ws_s,
                                  const int* __restrict__ start, int* __restrict__ cur,
                                  unsigned int* __restrict__ pw, int nptot, int Mb) {
  int t = blockIdx.x*blockDim.x + threadIdx.x;
  bool valid = (t < nptot);
  int m = 0, pix = 0; float w = 0.f;
  if (valid) {
    if (t < 6*NPIX) { int j = t >> 18, n = t & (NPIX-1); m = os_b[n*6+j]; pix = n; w = ws_b[n*6+j]; }
    else { int t2 = t - 6*NPIX; int j = t2 >> 18, n = t2 & (NPIX-1);
           m = Mb + os_s[n*3+j]; pix = n; w = ws_s[n*3+j]; }
  }
  int slot = wave_rank_atomic(m, valid, cur);
  if (valid) {
    int w14 = (int)(w * 16383.f + 0.5f);
    w14 = w14 < 0 ? 0 : (w14 > 16383 ? 16383 : w14);
    pw[start[m] + slot] = ((unsigned int)pix << 14) | (unsigned int)w14;
  }
}

// ---------------- lattice ops ----------------

// gather splat, wave-per-lattice-point: 5 pair-groups (CONTIGUOUS chunks of the
// list, uint2 pw loads, 4-entry unroll) x 11 half2 chunks + shfl reduce.
// ch21 of value row = weight sum (norm). (entry math identical to round-12)
__global__ void gather_half2_kernel(const __half* __restrict__ Qh, const int* __restrict__ start,
                                    const unsigned int* __restrict__ pw,
                                    __half* __restrict__ valsB, __half* __restrict__ valsS,
                                    int Mb, int Mtot) {
  int wid = blockIdx.x*(blockDim.x >> 6) + (threadIdx.x >> 6);
  if (wid >= Mtot) return;
  int lane = threadIdx.x & 63;
  int pg = lane/11;                    // 0..5 (pg==5 -> lanes 55..63 idle)
  int c2 = lane - pg*11;               // half2 chunk 0..10
  int k0 = start[wid], k1 = start[wid+1];
  float ax = 0.f, ay = 0.f, wsum = 0.f;
  if (pg < 5) {
    int len = k1 - k0;
    int L = (len + 4) / 5;             // per-group contiguous chunk
    int ka = k0 + pg*L;
    int kb = ka + L; if (kb > k1) kb = k1;
    int k = ka;
    // align to even k for uint2 loads
    if (k < kb && (k & 1)) {
      unsigned int e0 = pw[k];
      float w0 = (float)(e0 & 4095u);
      float2 f0 = __half22float2(*(const __half2*)(Qh + ((size_t)(e0 >> 12) << 5) + 2*c2));
      ax += w0*f0.x; ay += w0*f0.y; wsum += w0;
      ++k;
    }
    for (; k + 3 < kb; k += 4) {
      uint2 ea = *(const uint2*)(pw + k);
      uint2 eb = *(const uint2*)(pw + k + 2);
      float w0 = (float)(ea.x & 4095u), w1 = (float)(ea.y & 4095u);
      float w2 = (float)(eb.x & 4095u), w3 = (float)(eb.y & 4095u);
      float2 f0 = __half22float2(*(const __half2*)(Qh + ((size_t)(ea.x >> 12) << 5) + 2*c2));
      float2 f1 = __half22float2(*(const __half2*)(Qh + ((size_t)(ea.y >> 12) << 5) + 2*c2));
      float2 f2 = __half22float2(*(const __half2*)(Qh + ((size_t)(eb.x >> 12) << 5) + 2*c2));
      float2 f3 = __half22float2(*(const __half2*)(Qh + ((size_t)(eb.y >> 12) << 5) + 2*c2));
      ax += w0*f0.x + w1*f1.x + w2*f2.x + w3*f3.x;
      ay += w0*f0.y + w1*f1.y + w2*f2.y + w3*f3.y;
      wsum += w0 + w1 + w2 + w3;
    }
    for (; k < kb; ++k) {
      unsigned int e0 = pw[k];
      float w0 = (float)(e0 & 4095u);
      float2 f0 = __half22float2(*(const __half2*)(Qh + ((size_t)(e0 >> 12) << 5) + 2*c2));
      ax += w0*f0.x; ay += w0*f0.y; wsum += w0;
    }
  }
  float sx = ax, sy = ay, wt = wsum;
  #pragma unroll
  for (int g = 1; g < 5; ++g) {
    sx += __shfl(ax, lane + 11*g);
    sy += __shfl(ay, lane + 11*g);
    wt += __shfl(wsum, lane + 11*g);
  }
  if (lane < 11) {
    __half* row = (wid < Mb) ? (valsB + (size_t)(wid+1)*VSH)
                             : (valsS + (size_t)(wid-Mb+1)*VSH);
    float hy = (lane == 10) ? wt : sy;   // value ch21 = weight sum (norm)
    *(__half2*)(row + 2*lane) = __floats2half2_rn(sx*DECODE12, hy*DECODE12);
  }
}

// fallback gather (14-bit pw), 3x21 scalar layout
__global__ void gather_wave_kernel(const __half* __restrict__ Qh, const int* __restrict__ start,
                                   const unsigned int* __restrict__ pw,
                                   __half* __restrict__ valsB, __half* __restrict__ valsS,
                                   int Mb, int Mtot) {
  const unsigned int WMASK = (1u << 14) - 1u;
  int wid = blockIdx.x*(blockDim.x >> 6) + (threadIdx.x >> 6);
  if (wid >= Mtot) return;
  int lane = threadIdx.x & 63;
  int pg = lane / 21;
  int c  = lane - pg*21;
  float s = 0.f, wsum = 0.f;
  int k1 = start[wid+1];
  if (pg < 3) {
    int k = start[wid] + pg;
    for (; k + 9 < k1; k += 12) {
      unsigned int a0 = pw[k], a1 = pw[k+3], a2 = pw[k+6], a3 = pw[k+9];
      float w0 = (float)(a0 & WMASK), w1 = (float)(a1 & WMASK);
      float w2 = (float)(a2 & WMASK), w3 = (float)(a3 & WMASK);
      s += w0 * __half2float(Qh[((size_t)(a0 >> 14) << 5) + c])
         + w1 * __half2float(Qh[((size_t)(a1 >> 14) << 5) + c])
         + w2 * __half2float(Qh[((size_t)(a2 >> 14) << 5) + c])
         + w3 * __half2float(Qh[((size_t)(a3 >> 14) << 5) + c]);
      wsum += w0 + w1 + w2 + w3;
    }
    for (; k < k1; k += 3) {
      unsigned int a = pw[k];
      float w = (float)(a & WMASK);
      s += w * __half2float(Qh[((size_t)(a >> 14) << 5) + c]);
      wsum += w;
    }
  }
  float s1 = __shfl(s, (lane + 21) & 63);
  float s2 = __shfl(s, (lane + 42) & 63);
  float wt = __shfl(wsum, 0) + __shfl(wsum, 21) + __shfl(wsum, 42);
  __half* row = (wid < Mb) ? (valsB + (size_t)(wid+1)*VSH)
                           : (valsS + (size_t)(wid-Mb+1)*VSH);
  if (lane < 21)       row[c]  = __float2half((s + s1 + s2) * DECODE14);
  else if (lane == 21) row[21] = __float2half(wt * DECODE14);
}

// blur: 4 threads per row, float4 (16B) chunks, fp32 math on half2 components.
__global__ void blurH4_fused_kernel(const __half* __restrict__ inB, __half* __restrict__ outB,
                                    const int* __restrict__ bnB, int Mb,
                                    const __half* __restrict__ inS, __half* __restrict__ outS,
                                    const int* __restrict__ bnS, int Ms) {
  int t = blockIdx.x*blockDim.x + threadIdx.x;
  const __half* in; __half* out; const int* bn; int i, q;
  int tb = Mb*4;
  if (t < tb) { i = t>>2; q = t&3; in = inB; out = outB; bn = bnB; }
  else {
    int t2 = t - tb;
    if (t2 >= Ms*4) return;
    i = t2>>2; q = t2&3; in = inS; out = outS; bn = bnS;
  }
  int b0 = bn[2*i], b1 = bn[2*i+1];
  float4 A = ((const float4*)(in + (size_t)(i+1)*VSH))[q];
  float4 X = ((const float4*)(in + (size_t)b0*VSH))[q];
  float4 Y = ((const float4*)(in + (size_t)b1*VSH))[q];
  float4 O;
  const float* Af = (const float*)&A;
  const float* Xf = (const float*)&X;
  const float* Yf = (const float*)&Y;
  float* Of = (float*)&O;
  #pragma unroll
  for (int u = 0; u < 4; ++u) {
    float2 a = bits2f2(Af[u]);
    float2 x = bits2f2(Xf[u]);
    float2 y = bits2f2(Yf[u]);
    Of[u] = f22bits(a.x + 0.5f*(x.x + y.x), a.y + 0.5f*(x.y + y.y));
  }
  ((float4*)(out + (size_t)(i+1)*VSH))[q] = O;
}

// ---------------- pixel-side kernels ----------------

// init + fold-in of the 4 sentinel-row zeroings (rows 0 of value buffers)
__global__ void softmax_init_kernel(const float* __restrict__ U, __half* __restrict__ Qh,
                                    __half* __restrict__ Uh,
                                    __half* __restrict__ vAb, __half* __restrict__ vBb,
                                    __half* __restrict__ vAs, __half* __restrict__ vBs) {
  int n = blockIdx.x*blockDim.x + threadIdx.x;
  if (blockIdx.x == 0 && threadIdx.x < 64) {
    int t = threadIdx.x & 15;
    __half* rows[4] = {vAb, vBb, vAs, vBs};
    ((float*)rows[threadIdx.x >> 4])[t] = 0.f;
  }
  if (n >= NPIX) return;
  float l[NCH];
  float m = -3.4e38f;
  #pragma unroll
  for (int c = 0; c < NCH; ++c) {
    l[c] = -U[(size_t)n*NCH+c];
    m = fmaxf(m, l[c]);
  }
  {
    float buf[11];
    #pragma unroll
    for (int i = 0; i < 10; ++i) buf[i] = f22bits(l[2*i], l[2*i+1]);
    buf[10] = f22bits(l[20], 0.f);
    __half* u = Uh + (size_t)n*USH;
    *(float4*)(u)      = *(float4*)&buf[0];
    *(float4*)(u + 8)  = *(float4*)&buf[4];
    *(float2*)(u + 16) = *(float2*)&buf[8];
    *(float*)(u + 20)  = buf[10];
  }
  float s = 0.f;
  #pragma unroll
  for (int c = 0; c < NCH; ++c) { l[c] = expf(l[c]-m); s += l[c]; }
  float r = 1.0f/s;
  #pragma unroll
  for (int c = 0; c < NCH; ++c) l[c] *= r;
  {
    float buf[11];
    #pragma unroll
    for (int i = 0; i < 10; ++i) buf[i] = f22bits(l[2*i], l[2*i+1]);
    buf[10] = f22bits(l[20], 0.f);   // ch21 = 0 for half2 gather
    __half* q = Qh + (size_t)n*QSH;
    *(float4*)(q)      = *(float4*)&buf[0];
    *(float4*)(q + 8)  = *(float4*)&buf[4];
    *(float2*)(q + 16) = *(float2*)&buf[8];
    *(float*)(q + 20)  = buf[10];
  }
}

__device__ __forceinline__ void accum_row(const __half* __restrict__ v, float w, float2* acc2) {
  float4 a = *(const float4*)(v);
  float4 b = *(const float4*)(v + 8);
  float2 c = *(const float2*)(v + 16);
  float  d = *(const float*)(v + 20);
  float buf[11] = {a.x, a.y, a.z, a.w, b.x, b.y, b.z, b.w, c.x, c.y, d};
  #pragma unroll
  for (int i = 0; i < 11; ++i) {
    float2 f = bits2f2(buf[i]);
    acc2[i].x += w*f.x;
    acc2[i].y += w*f.y;
  }
}

template<bool FINAL, bool PACKED>
__global__ void slice_combine_softmax_kernel(
    const __half* __restrict__ Uh,
    const __half* __restrict__ vb, const __half* __restrict__ vsShift,
    const unsigned int* __restrict__ sl,
    const float* __restrict__ ws_b, const int* __restrict__ os_b,
    const float* __restrict__ ws_s, const int* __restrict__ os_s,
    float* __restrict__ QoutF, __half* __restrict__ QoutH) {
  int n = blockIdx.x*blockDim.x + threadIdx.x;
  if (n >= NPIX) return;
  float l[NCH];
  {
    const __half* u = Uh + (size_t)n*USH;
    float4 a = *(const float4*)(u);
    float4 b = *(const float4*)(u + 8);
    float2 c = *(const float2*)(u + 16);
    float buf[10] = {a.x, a.y, a.z, a.w, b.x, b.y, b.z, b.w, c.x, c.y};
    #pragma unroll
    for (int i = 0; i < 10; ++i) {
      float2 f = bits2f2(buf[i]);
      l[2*i] = f.x; l[2*i+1] = f.y;
    }
    l[20] = __half2float(u[20]);
  }
  float2 acc2[11];
  #pragma unroll
  for (int i = 0; i < 11; ++i) acc2[i] = make_float2(0.f, 0.f);
  #pragma unroll
  for (int j = 0; j < 6; ++j) {
    float w; const __half* v;
    if (PACKED) {
      unsigned int e = sl[(size_t)j*NPIX + n];
      w = (float)(e & 4095u);
      v = vb + ((size_t)(e >> 12) << 5);
    } else {
      w = ws_b[n*6+j];
      v = vb + (size_t)(os_b[n*6+j]+1)*VSH;
    }
    accum_row(v, w, acc2);
  }
  {
    float rb = 10.0f/(acc2[10].y + 1e-12f);   // ch21 = norm
    #pragma unroll
    for (int i = 0; i < 10; ++i) { l[2*i] += rb*acc2[i].x; l[2*i+1] += rb*acc2[i].y; }
    l[20] += rb*acc2[10].x;
  }
  #pragma unroll
  for (int i = 0; i < 11; ++i) acc2[i] = make_float2(0.f, 0.f);
  #pragma unroll
  for (int j = 0; j < 3; ++j) {
    float w; const __half* v;
    if (PACKED) {
      unsigned int e = sl[(size_t)(6+j)*NPIX + n];
      w = (float)(e & 4095u);
      v = vsShift + ((size_t)(e >> 12) << 5);
    } else {
      w = ws_s[n*3+j];
      v = vsShift + (size_t)(os_s[n*3+j]+1)*VSH;
    }
    accum_row(v, w, acc2);
  }
  {
    float rs = 3.0f/(acc2[10].y + 1e-12f);
    #pragma unroll
    for (int i = 0; i < 10; ++i) { l[2*i] += rs*acc2[i].x; l[2*i+1] += rs*acc2[i].y; }
    l[20] += rs*acc2[10].x;
  }
  float m = -3.4e38f;
  #pragma unroll
  for (int c = 0; c < NCH; ++c) m = fmaxf(m, l[c]);
  float s = 0.f;
  #pragma unroll
  for (int c = 0; c < NCH; ++c) { l[c] = expf(l[c]-m); s += l[c]; }
  float r = 1.0f/s;
  if (FINAL) {
    #pragma unroll
    for (int c = 0; c < NCH; ++c) QoutF[(size_t)n*NCH+c] = l[c]*r;
  } else {
    float buf[11];
    #pragma unroll
    for (int i = 0; i < 10; ++i) buf[i] = f22bits(l[2*i]*r, l[2*i+1]*r);
    buf[10] = f22bits(l[20]*r, 0.f);
    __half* q = QoutH + (size_t)n*QSH;
    *(float4*)(q)      = *(float4*)&buf[0];
    *(float4*)(q + 8)  = *(float4*)&buf[4];
    *(float2*)(q + 16) = *(float2*)&buf[8];
    *(float*)(q + 20)  = buf[10];
  }
}

// ---------------- host ----------------

extern "C" void kernel_launch(void* const* d_in, const int* in_sizes, int n_in,
                              void* d_out, int out_size, void* d_ws, size_t ws_size,
                              hipStream_t stream) {
  const float* U    = (const float*)d_in[0];
  const float* ws_b = (const float*)d_in[1];
  const float* ws_s = (const float*)d_in[2];
  const int*   os_b = (const int*)d_in[3];
  const int*   os_s = (const int*)d_in[4];
  const int*   bn_b = (const int*)d_in[5];
  const int*   bn_s = (const int*)d_in[6];
  const int Mb = in_sizes[5] / 12;
  const int Ms = in_sizes[6] / 6;
  const int Mtot = Mb + Ms;
  const int nptot = NPIX*9;
  const bool packed = (Mtot + 1) < (1 << 20);

  char* wcur = (char*)d_ws;
  auto alloc = [&](size_t bytes) -> void* {
    void* p = (void*)wcur;
    wcur += (bytes + 63) & ~(size_t)63;
    return p;
  };
  __half* Qh     = (__half*)alloc((size_t)NPIX*QSH*2);
  __half* Uh     = (__half*)alloc((size_t)NPIX*USH*2);
  __half* vAb    = (__half*)alloc((size_t)(Mb+1)*VSH*2);
  __half* vBb    = (__half*)alloc((size_t)(Mb+1)*VSH*2);
  __half* vAs    = (__half*)alloc((size_t)(Ms+1)*VSH*2);
  __half* vBs    = (__half*)alloc((size_t)(Ms+1)*VSH*2);
  int*   start   = (int*)alloc((size_t)(Mtot+1)*4);
  int*   cur     = (int*)alloc((size_t)Mtot*4);
  unsigned int* pw = (unsigned int*)alloc((size_t)nptot*4);
  unsigned int* sl = (unsigned int*)alloc((size_t)nptot*4);
  int*   bsum    = (int*)alloc((size_t)(Mtot/256 + 3)*4);

  const int TB = 256;
  auto blocks = [](long long n){ return (int)((n + 255)/256); };
  const int nbM = blocks(Mtot);

  // ---- build: pack+count (per-pixel, coalesced), scan, fill ----
  hipMemsetAsync(cur, 0, (size_t)Mtot*sizeof(int), stream);
  if (packed)
    pack9_count_kernel<<<blocks(NPIX), TB, 0, stream>>>(os_b, ws_b, os_s, ws_s,
                                                        sl, cur, Mb);
  else
    count_fused_kernel<<<blocks(nptot), TB, 0, stream>>>(os_b, os_s, cur, nptot, Mb);
  scan_block_kernel<<<nbM, 256, 0, stream>>>(cur, start, bsum, Mtot);
  scan_sums_kernel<<<1, 256, 0, stream>>>(bsum, nbM);
  scan_add_kernel<<<blocks(Mtot+1), TB, 0, stream>>>(start, bsum, Mtot, nbM);
  hipMemsetAsync(cur, 0, (size_t)Mtot*sizeof(int), stream);
  if (packed)
    fill_packed_kernel<<<blocks(nptot), TB, 0, stream>>>(sl, start, cur, pw, nptot);
  else
    fill_fused_kernel<<<blocks(nptot), TB, 0, stream>>>(os_b, ws_b, os_s, ws_s,
                                                        start, cur, pw, nptot, Mb);

  // init (also zeroes sentinel row 0 of the 4 value buffers)
  softmax_init_kernel<<<blocks(NPIX), TB, 0, stream>>>(U, Qh, Uh, vAb, vBb, vAs, vBs);

  for (int it = 0; it < 5; ++it) {
    if (packed)
      gather_half2_kernel<<<blocks((long long)Mtot*64), TB, 0, stream>>>(
          Qh, start, pw, vAb, vAs, Mb, Mtot);
    else
      gather_wave_kernel<<<blocks((long long)Mtot*64), TB, 0, stream>>>(
          Qh, start, pw, vAb, vAs, Mb, Mtot);
    __half* ab = vAb; __half* bb = vBb;
    __half* as = vAs; __half* bs = vBs;
    for (int j = 0; j < 6; ++j) {
      int ms = (j < 3) ? Ms : 0;
      blurH4_fused_kernel<<<blocks((long long)(Mb + ms)*4), TB, 0, stream>>>(
          ab, bb, bn_b + (size_t)j*Mb*2, Mb, as, bs, bn_s + (size_t)j*Ms*2, ms);
      { __half* t = ab; ab = bb; bb = t; }
      if (j < 3) { __half* t = as; as = bs; bs = t; }
    }
    // ab = final bilateral (vAb), as = final spatial (vBs)
    const __half* vsArg = packed ? (as - (size_t)Mb*VSH) : as;
    if (it == 4) {
      if (packed)
        slice_combine_softmax_kernel<true,true><<<blocks(NPIX), TB, 0, stream>>>(
            Uh, ab, vsArg, sl, ws_b, os_b, ws_s, os_s, (float*)d_out, (__half*)nullptr);
      else
        slice_combine_softmax_kernel<true,false><<<blocks(NPIX), TB, 0, stream>>>(
            Uh, ab, vsArg, sl, ws_b, os_b, ws_s, os_s, (float*)d_out, (__half*)nullptr);
    } else {
      if (packed)
        slice_combine_softmax_kernel<false,true><<<blocks(NPIX), TB, 0, stream>>>(
            Uh, ab, vsArg, sl, ws_b, os_b, ws_s, os_s, (float*)nullptr, Qh);
      else
        slice_combine_softmax_kernel<false,false><<<blocks(NPIX), TB, 0, stream>>>(
            Uh, ab, vsArg, sl, ws_b, os_b, ws_s, os_s, (float*)nullptr, Qh);
    }
  }
}